// Round 3
// baseline (397.928 us; speedup 1.0000x reference)
//
#include <hip/hip_runtime.h>
#include <math.h>

// Problem constants (fixed by the reference)
#define BB 128          // batch
#define CC 100000       // classes
#define FF 256          // feature dim
#define KB 32           // K-chunk staged in LDS
#define NB 64           // classes per workgroup
#define NWG ((CC + NB - 1) / NB)   // 1563
#define SCALARF 20.0f
#define F4C(v, j) ((&(v).x)[j])

// Column-slot XOR swizzle: slot s -> s ^ ((s>>3)&7). Bijective within a row;
// makes the 8 distinct b128 read addresses per wave land on distinct bank
// groups (<=2-way aliasing = free). Same map used on write and read.
__device__ __forceinline__ int swz(int s) { return s ^ ((s >> 3) & 7); }

// ---------------------------------------------------------------------------
// K1: fused dual-GEMM + split-softmax partials + smooth-L1 partial.
// Grid: NWG blocks x 128 threads. Each block: 64 classes x 128 samples x 2 luts.
// Per thread: 8 samples x 8 classes x 2 luts = 128 fp32 accumulators.
// ---------------------------------------------------------------------------
__global__ __launch_bounds__(128, 2) void k_main(
    const float* __restrict__ inputs,   // [128][256]
    const float* __restrict__ lutc,     // [100000][256]
    const float* __restrict__ luti,     // [100000][256]
    float* __restrict__ maxp,           // [2][128][NWG]
    float* __restrict__ sep,            // [2][128][NWG]
    float* __restrict__ slp,            // [2][128][NWG]
    float* __restrict__ hubp)           // [NWG]
{
    __shared__ float sIn[KB][BB];   // [32][128], transposed+swizzled, pre-scaled by 20
    __shared__ float sLc[KB][NB];   // [32][64]
    __shared__ float sLi[KB][NB];
    __shared__ float hsh[2];

    const int tid = threadIdx.x;
    const int tn  = tid & 7;     // class group (8 classes each)
    const int tm  = tid >> 3;    // sample group (8 samples each), 0..15
    const int wg  = blockIdx.x;
    const int cbase = wg * NB;

    float acc[2][8][8];
#pragma unroll
    for (int l = 0; l < 2; ++l)
#pragma unroll
        for (int i = 0; i < 8; ++i)
#pragma unroll
            for (int j = 0; j < 8; ++j) acc[l][i][j] = 0.f;

    // Loop-invariant LDS read offsets (floats within a row)
    const int aOff0 = 4 * swz(2 * tm);
    const int aOff1 = 4 * swz(2 * tm + 1);
    const int bOff0 = 4 * swz(2 * tn);
    const int bOff1 = 4 * swz(2 * tn + 1);

    const float4 z4 = make_float4(0.f, 0.f, 0.f, 0.f);

    for (int it = 0; it < FF / KB; ++it) {
        const int k0 = it * KB;
        __syncthreads();   // previous tile fully consumed before overwrite

        // ---- stage inputs (transpose 4x4 in registers, scale by 20) ----
#pragma unroll
        for (int r = 0; r < 2; ++r) {
            int task = r * 128 + tid;          // 0..255
            int bg = task >> 3;                // 4-sample group 0..31
            int qq = task & 7;                 // float4 along k
            const float* src = inputs + (size_t)(bg * 4) * FF + k0 + qq * 4;
            float4 v0 = *(const float4*)(src);
            float4 v1 = *(const float4*)(src + FF);
            float4 v2 = *(const float4*)(src + 2 * FF);
            float4 v3 = *(const float4*)(src + 3 * FF);
            int wc = 4 * swz(bg);
#pragma unroll
            for (int j = 0; j < 4; ++j) {
                float4 t = make_float4(F4C(v0, j) * SCALARF, F4C(v1, j) * SCALARF,
                                       F4C(v2, j) * SCALARF, F4C(v3, j) * SCALARF);
                *(float4*)&sIn[qq * 4 + j][wc] = t;
            }
        }
        // ---- stage lut tiles (zero-pad tail classes; harmless, see notes) ----
        {
            int ng = tid >> 3;                 // 4-class group 0..15
            int qq = tid & 7;
            int c0 = cbase + ng * 4;
            int wc = 4 * swz(ng);
            const float* srcc = lutc + (size_t)c0 * FF + k0 + qq * 4;
            float4 v0 = (c0 + 0 < CC) ? *(const float4*)(srcc)          : z4;
            float4 v1 = (c0 + 1 < CC) ? *(const float4*)(srcc + FF)     : z4;
            float4 v2 = (c0 + 2 < CC) ? *(const float4*)(srcc + 2 * FF) : z4;
            float4 v3 = (c0 + 3 < CC) ? *(const float4*)(srcc + 3 * FF) : z4;
#pragma unroll
            for (int j = 0; j < 4; ++j) {
                *(float4*)&sLc[qq * 4 + j][wc] =
                    make_float4(F4C(v0, j), F4C(v1, j), F4C(v2, j), F4C(v3, j));
            }
            const float* srci = luti + (size_t)c0 * FF + k0 + qq * 4;
            v0 = (c0 + 0 < CC) ? *(const float4*)(srci)          : z4;
            v1 = (c0 + 1 < CC) ? *(const float4*)(srci + FF)     : z4;
            v2 = (c0 + 2 < CC) ? *(const float4*)(srci + 2 * FF) : z4;
            v3 = (c0 + 3 < CC) ? *(const float4*)(srci + 3 * FF) : z4;
#pragma unroll
            for (int j = 0; j < 4; ++j) {
                *(float4*)&sLi[qq * 4 + j][wc] =
                    make_float4(F4C(v0, j), F4C(v1, j), F4C(v2, j), F4C(v3, j));
            }
        }
        __syncthreads();

        // ---- compute: 32 k-steps x (8 samples x 8 classes x 2 luts) ----
#pragma unroll 4
        for (int kk = 0; kk < KB; ++kk) {
            const float* rI = sIn[kk];
            const float* rC = sLc[kk];
            const float* rJ = sLi[kk];
            float4 a0 = *(const float4*)(rI + aOff0);
            float4 a1 = *(const float4*)(rI + aOff1);
            float4 c0 = *(const float4*)(rC + bOff0);
            float4 c1 = *(const float4*)(rC + bOff1);
            float4 d0 = *(const float4*)(rJ + bOff0);
            float4 d1 = *(const float4*)(rJ + bOff1);
            float aR[8] = {a0.x, a0.y, a0.z, a0.w, a1.x, a1.y, a1.z, a1.w};
            float bC[8] = {c0.x, c0.y, c0.z, c0.w, c1.x, c1.y, c1.z, c1.w};
            float bI[8] = {d0.x, d0.y, d0.z, d0.w, d1.x, d1.y, d1.z, d1.w};
#pragma unroll
            for (int i = 0; i < 8; ++i)
#pragma unroll
                for (int j = 0; j < 8; ++j) {
                    acc[0][i][j] = fmaf(aR[i], bC[j], acc[0][i][j]);
                    acc[1][i][j] = fmaf(aR[i], bI[j], acc[1][i][j]);
                }
        }
    }

    // ---- epilogue: smooth-L1 partial (both tiles in-register) ----
    float hloc = 0.f;
#pragma unroll
    for (int i = 0; i < 8; ++i)
#pragma unroll
        for (int j = 0; j < 8; ++j) {
            float d = fabsf(acc[0][i][j] - acc[1][i][j]);
            hloc += (d < 1.f) ? 0.5f * d * d : d - 0.5f;
        }

    // ---- epilogue: per-sample split-softmax partials (8-lane reductions) ----
#pragma unroll
    for (int l = 0; l < 2; ++l) {
#pragma unroll
        for (int i = 0; i < 8; ++i) {
            float mx = acc[l][i][0];
#pragma unroll
            for (int j = 1; j < 8; ++j) mx = fmaxf(mx, acc[l][i][j]);
            mx = fmaxf(mx, __shfl_xor(mx, 1));
            mx = fmaxf(mx, __shfl_xor(mx, 2));
            mx = fmaxf(mx, __shfl_xor(mx, 4));
            float se = 0.f, sl = 0.f;
#pragma unroll
            for (int j = 0; j < 8; ++j) {
                se += __expf(acc[l][i][j] - mx);
                sl += acc[l][i][j];
            }
            se += __shfl_xor(se, 1); se += __shfl_xor(se, 2); se += __shfl_xor(se, 4);
            sl += __shfl_xor(sl, 1); sl += __shfl_xor(sl, 2); sl += __shfl_xor(sl, 4);
            if (tn == 0) {
                int b = tm * 8 + i;
                size_t o = ((size_t)(l * BB + b)) * NWG + wg;
                maxp[o] = mx; sep[o] = se; slp[o] = sl;
            }
        }
    }

    // ---- huber block reduction ----
#pragma unroll
    for (int off = 1; off < 64; off <<= 1) hloc += __shfl_xor(hloc, off);
    if ((tid & 63) == 0) hsh[tid >> 6] = hloc;
    __syncthreads();
    if (tid == 0) hubp[wg] = hsh[0] + hsh[1];
}

// ---------------------------------------------------------------------------
// K2: combine split-softmax partials per (lut, sample); target logit dot.
// Grid: 256 blocks (lut*128+b) x 64 threads.
// ---------------------------------------------------------------------------
__global__ __launch_bounds__(64) void k_reduce(
    const float* __restrict__ inputs, const int* __restrict__ targets,
    const float* __restrict__ lutc, const float* __restrict__ luti,
    const float* __restrict__ maxp, const float* __restrict__ sep,
    const float* __restrict__ slp, float* __restrict__ vvals)
{
    const int l = blockIdx.x >> 7;
    const int b = blockIdx.x & 127;
    const int lane = threadIdx.x;
    const size_t base = ((size_t)(l * BB + b)) * NWG;

    float M = -1e30f, S = 0.f, SL = 0.f;
    for (int w = lane; w < NWG; w += 64) {
        float m = maxp[base + w];
        float s = sep[base + w];
        float nM = fmaxf(M, m);
        S = S * __expf(M - nM) + s * __expf(m - nM);
        M = nM;
        SL += slp[base + w];
    }
#pragma unroll
    for (int off = 1; off < 64; off <<= 1) {
        float m2 = __shfl_xor(M, off), s2 = __shfl_xor(S, off), sl2 = __shfl_xor(SL, off);
        float nM = fmaxf(M, m2);
        S = S * __expf(M - nM) + s2 * __expf(m2 - nM);
        M = nM;
        SL += sl2;
    }

    // target logit: 64-lane dot over 256 features
    const int tgt = targets[b];
    const float* lut = (l == 0 ? lutc : luti) + (size_t)tgt * FF;
    const float* inp = inputs + (size_t)b * FF;
    float4 x = *(const float4*)(inp + lane * 4);
    float4 y = *(const float4*)(lut + lane * 4);
    float dp = x.x * y.x + x.y * y.y + x.z * y.z + x.w * y.w;
#pragma unroll
    for (int off = 1; off < 64; off <<= 1) dp += __shfl_xor(dp, off);

    if (lane == 0) {
        float lt  = SCALARF * dp;
        float lse = M + __logf(S);
        // (1-eps)*(lse - l_t) + eps*(lse - mean(logits))
        vvals[blockIdx.x] = 0.9f * (lse - lt) + 0.1f * (lse - SL / (float)CC);
    }
}

// ---------------------------------------------------------------------------
// K3: final scalar reduction.
// ---------------------------------------------------------------------------
__global__ __launch_bounds__(256) void k_final(
    const float* __restrict__ vvals, const float* __restrict__ hubp,
    float* __restrict__ out)
{
    __shared__ float sv[4], sh2[4];
    const int tid = threadIdx.x;
    float v = vvals[tid];            // exactly 256 values
    float h = 0.f;
    for (int w = tid; w < NWG; w += 256) h += hubp[w];
#pragma unroll
    for (int off = 1; off < 64; off <<= 1) {
        v += __shfl_xor(v, off);
        h += __shfl_xor(h, off);
    }
    if ((tid & 63) == 0) { sv[tid >> 6] = v; sh2[tid >> 6] = h; }
    __syncthreads();
    if (tid == 0) {
        float sumv = sv[0] + sv[1] + sv[2] + sv[3];
        float sumh = sh2[0] + sh2[1] + sh2[2] + sh2[3];
        out[0] = sumv / (float)BB + 0.25f * sumh / ((float)BB * (float)CC);
    }
}

extern "C" void kernel_launch(void* const* d_in, const int* in_sizes, int n_in,
                              void* d_out, int out_size, void* d_ws, size_t ws_size,
                              hipStream_t stream) {
    const float* inputs  = (const float*)d_in[0];
    const int*   targets = (const int*)d_in[1];
    const float* lutc    = (const float*)d_in[2];
    const float* luti    = (const float*)d_in[3];
    float* out = (float*)d_out;
    float* ws  = (float*)d_ws;

    // ws layout (floats): maxp | sep | slp | hubp | vvals  (~4.81 MB total)
    const size_t statN = (size_t)2 * BB * NWG;   // 400128
    float* maxp  = ws;
    float* sep   = ws + statN;
    float* slp   = ws + 2 * statN;
    float* hubp  = ws + 3 * statN;
    float* vvals = hubp + NWG;

    k_main<<<NWG, 128, 0, stream>>>(inputs, lutc, luti, maxp, sep, slp, hubp);
    k_reduce<<<256, 64, 0, stream>>>(inputs, targets, lutc, luti, maxp, sep, slp, vvals);
    k_final<<<1, 256, 0, stream>>>(vvals, hubp, out);
}

// Round 4
// 354.449 us; speedup vs baseline: 1.1227x; 1.1227x over previous
//
#include <hip/hip_runtime.h>
#include <math.h>

// Problem constants (fixed by the reference)
#define BB 128          // batch
#define CC 100000       // classes
#define FF 256          // feature dim
#define NB 64           // classes per workgroup (4 waves x 16 cols)
#define NWG ((CC + NB - 1) / NB)   // 1563
#define SCALARF 20.0f

typedef __attribute__((ext_vector_type(8))) short short8;   // 8 bf16 = 4 VGPR (MFMA A/B frag)
typedef __attribute__((ext_vector_type(4))) float f32x4;    // MFMA C/D frag

// ---- fp32 -> bf16 split helpers (RNE via bit trick; deterministic) ----
__device__ __forceinline__ unsigned short bf16_rne(float f) {
    unsigned int u = __float_as_uint(f);
    u += 0x7FFFu + ((u >> 16) & 1u);
    return (unsigned short)(u >> 16);
}
__device__ __forceinline__ float bf16_to_f32(unsigned short h) {
    return __uint_as_float((unsigned int)h << 16);
}

// ---------------------------------------------------------------------------
// K0: pre-split scaled inputs (x20) into MFMA A-fragment layout, hi/lo bf16.
// Layout (ushort units): wsA[((kc*8+mt)*2+h)*512 + lane*8 + j]
//   = bf16_part_h( 20 * inputs[(lane&15)+16*mt][kc*32 + (lane>>4)*8 + j] )
// Same positional k-map as the B-frag loads in K1 -> HW k-permutation cancels.
// 4096 tasks: grid 16 x 256.
// ---------------------------------------------------------------------------
__global__ __launch_bounds__(256) void k_prep(const float* __restrict__ inputs,
                                              unsigned short* __restrict__ wsA)
{
    int t    = blockIdx.x * 256 + threadIdx.x;   // 0..4095
    int lane = t & 63;
    int mt   = (t >> 6) & 7;
    int kc   = t >> 9;
    int row  = (lane & 15) + 16 * mt;
    int k0   = kc * 32 + ((lane >> 4) << 3);
    const float* src = inputs + (size_t)row * FF + k0;
    float4 x0 = *(const float4*)(src);
    float4 x1 = *(const float4*)(src + 4);
    float v[8] = {x0.x, x0.y, x0.z, x0.w, x1.x, x1.y, x1.z, x1.w};
    unsigned short h[8], l[8];
#pragma unroll
    for (int j = 0; j < 8; ++j) {
        float a = v[j] * SCALARF;
        h[j] = bf16_rne(a);
        l[j] = bf16_rne(a - bf16_to_f32(h[j]));
    }
    size_t base = (size_t)(kc * 8 + mt) * 2 * 512;   // frag = 512 ushorts = 1KB
    uint4 ph, pl;
    ph.x = (unsigned)h[0] | ((unsigned)h[1] << 16);
    ph.y = (unsigned)h[2] | ((unsigned)h[3] << 16);
    ph.z = (unsigned)h[4] | ((unsigned)h[5] << 16);
    ph.w = (unsigned)h[6] | ((unsigned)h[7] << 16);
    pl.x = (unsigned)l[0] | ((unsigned)l[1] << 16);
    pl.y = (unsigned)l[2] | ((unsigned)l[3] << 16);
    pl.z = (unsigned)l[4] | ((unsigned)l[5] << 16);
    pl.w = (unsigned)l[6] | ((unsigned)l[7] << 16);
    *(uint4*)(wsA + base + lane * 8)       = ph;
    *(uint4*)(wsA + base + 512 + lane * 8) = pl;
}

// ---------------------------------------------------------------------------
// K1: dual-GEMM via bf16-split MFMA (Ah*Bh + Al*Bh + Ah*Bl), no LDS staging.
// Block = 256 thr = 4 waves; wave w owns 16 classes (cols), all 128 samples.
// B-frags load fp32 straight from the LUT stream (each element once),
// A-frags load pre-split bf16 from wsA (L1/L2-resident, shared by all waves).
// Per wave: acc = 2 luts x 8 M-tiles x f32x4 = 64 VGPR.
// ---------------------------------------------------------------------------
__global__ __launch_bounds__(256, 2) void k_main_mfma(
    const unsigned short* __restrict__ wsA,
    const float* __restrict__ lutc,
    const float* __restrict__ luti,
    float* __restrict__ maxp,           // [2][128][NWG]
    float* __restrict__ sep,            // [2][128][NWG]
    float* __restrict__ slp,            // [2][128][NWG]
    float* __restrict__ hubp)           // [NWG]
{
    __shared__ float sMax[2][4][128];
    __shared__ float sSe [2][4][128];
    __shared__ float sSl [2][4][128];
    __shared__ float hsh[4];

    const int tid  = threadIdx.x;
    const int w    = tid >> 6;        // wave 0..3
    const int lane = tid & 63;
    const int cg   = lane & 15;       // col within wave's 16
    const int g    = lane >> 4;       // k-subgroup / D-row group
    const int wg   = blockIdx.x;
    const int col  = wg * NB + w * 16 + cg;
    const bool valid = col < CC;
    const int colc = valid ? col : (CC - 1);

    const float* pC = lutc + (size_t)colc * FF + g * 8;
    const float* pI = luti + (size_t)colc * FF + g * 8;

    f32x4 acc[2][8];
#pragma unroll
    for (int l2 = 0; l2 < 2; ++l2)
#pragma unroll
        for (int mt = 0; mt < 8; ++mt) acc[l2][mt] = (f32x4)(0.0f);

    // ---- preload chunk 0's B fp32 (the HBM-critical stream) ----
    float4 nc0 = *(const float4*)(pC);
    float4 nc1 = *(const float4*)(pC + 4);
    float4 ni0 = *(const float4*)(pI);
    float4 ni1 = *(const float4*)(pI + 4);

#pragma unroll 1
    for (int kc = 0; kc < 8; ++kc) {
        // convert current B to hi/lo frags
        float vc[8] = {nc0.x, nc0.y, nc0.z, nc0.w, nc1.x, nc1.y, nc1.z, nc1.w};
        float vi[8] = {ni0.x, ni0.y, ni0.z, ni0.w, ni1.x, ni1.y, ni1.z, ni1.w};
        short8 bhC, blC, bhI, blI;
#pragma unroll
        for (int j = 0; j < 8; ++j) {
            unsigned short hc = bf16_rne(vc[j]);
            bhC[j] = (short)hc;
            blC[j] = (short)bf16_rne(vc[j] - bf16_to_f32(hc));
            unsigned short hi2 = bf16_rne(vi[j]);
            bhI[j] = (short)hi2;
            blI[j] = (short)bf16_rne(vi[j] - bf16_to_f32(hi2));
        }
        // issue next chunk's B loads (wraps harmlessly at kc=7)
        {
            int kn = (kc + 1) & 7;
            nc0 = *(const float4*)(pC + kn * 32);
            nc1 = *(const float4*)(pC + kn * 32 + 4);
            ni0 = *(const float4*)(pI + kn * 32);
            ni1 = *(const float4*)(pI + kn * 32 + 4);
        }
        // A-frags for this chunk (L1/L2 hits; shared across the block's waves)
        short8 aF[8][2];
#pragma unroll
        for (int mt = 0; mt < 8; ++mt) {
            const unsigned short* ab = wsA + (size_t)(kc * 8 + mt) * 2 * 512 + lane * 8;
            aF[mt][0] = *(const short8*)(ab);
            aF[mt][1] = *(const short8*)(ab + 512);
        }
        // 48 MFMAs: 8 M-tiles x 2 luts x 3 split-products
#pragma unroll
        for (int mt = 0; mt < 8; ++mt) {
            acc[0][mt] = __builtin_amdgcn_mfma_f32_16x16x32_bf16(aF[mt][0], bhC, acc[0][mt], 0, 0, 0);
            acc[0][mt] = __builtin_amdgcn_mfma_f32_16x16x32_bf16(aF[mt][1], bhC, acc[0][mt], 0, 0, 0);
            acc[0][mt] = __builtin_amdgcn_mfma_f32_16x16x32_bf16(aF[mt][0], blC, acc[0][mt], 0, 0, 0);
            acc[1][mt] = __builtin_amdgcn_mfma_f32_16x16x32_bf16(aF[mt][0], bhI, acc[1][mt], 0, 0, 0);
            acc[1][mt] = __builtin_amdgcn_mfma_f32_16x16x32_bf16(aF[mt][1], bhI, acc[1][mt], 0, 0, 0);
            acc[1][mt] = __builtin_amdgcn_mfma_f32_16x16x32_bf16(aF[mt][0], blI, acc[1][mt], 0, 0, 0);
        }
    }

    // ---- epilogue ----
    // D layout (m89-verified): col = lane&15 (class), row = 16*mt + 4*g + j (sample)

    // smooth-L1 partial (valid cols only)
    float hloc = 0.f;
#pragma unroll
    for (int mt = 0; mt < 8; ++mt)
#pragma unroll
        for (int j = 0; j < 4; ++j) {
            float d = fabsf(acc[0][mt][j] - acc[1][mt][j]);
            float hv = (d < 1.f) ? 0.5f * d * d : d - 0.5f;
            hloc += valid ? hv : 0.f;
        }

    // per-sample-row softmax partials over this wave's 16 cols
    // (16-lane group reduce: xor 1,2,4,8 stays within the group)
#pragma unroll
    for (int l2 = 0; l2 < 2; ++l2) {
#pragma unroll
        for (int mt = 0; mt < 8; ++mt) {
#pragma unroll
            for (int j = 0; j < 4; ++j) {
                float v  = acc[l2][mt][j];
                float mv = valid ? v : -3.0e38f;
                mv = fmaxf(mv, __shfl_xor(mv, 1));
                mv = fmaxf(mv, __shfl_xor(mv, 2));
                mv = fmaxf(mv, __shfl_xor(mv, 4));
                mv = fmaxf(mv, __shfl_xor(mv, 8));
                float e  = valid ? __expf(v - mv) : 0.f;
                float sl = valid ? v : 0.f;
                e  += __shfl_xor(e, 1);  e  += __shfl_xor(e, 2);
                e  += __shfl_xor(e, 4);  e  += __shfl_xor(e, 8);
                sl += __shfl_xor(sl, 1); sl += __shfl_xor(sl, 2);
                sl += __shfl_xor(sl, 4); sl += __shfl_xor(sl, 8);
                if (cg == 0) {
                    int r = 16 * mt + 4 * g + j;
                    sMax[l2][w][r] = mv;
                    sSe [l2][w][r] = e;
                    sSl [l2][w][r] = sl;
                }
            }
        }
    }

    // huber wave reduce -> block
#pragma unroll
    for (int off = 1; off < 64; off <<= 1) hloc += __shfl_xor(hloc, off);
    if (lane == 0) hsh[w] = hloc;
    __syncthreads();

    // combine 4 waves per (lut,row) and write global partials (K2-compatible)
    {
        int l2 = tid >> 7, r = tid & 127;
        float m0 = sMax[l2][0][r], m1 = sMax[l2][1][r];
        float m2 = sMax[l2][2][r], m3 = sMax[l2][3][r];
        float m  = fmaxf(fmaxf(m0, m1), fmaxf(m2, m3));
        float se = sSe[l2][0][r] * __expf(m0 - m) + sSe[l2][1][r] * __expf(m1 - m)
                 + sSe[l2][2][r] * __expf(m2 - m) + sSe[l2][3][r] * __expf(m3 - m);
        float sl = sSl[l2][0][r] + sSl[l2][1][r] + sSl[l2][2][r] + sSl[l2][3][r];
        size_t o = ((size_t)(l2 * BB + r)) * NWG + wg;
        maxp[o] = m; sep[o] = se; slp[o] = sl;
    }
    if (tid == 0) hubp[wg] = hsh[0] + hsh[1] + hsh[2] + hsh[3];
}

// ---------------------------------------------------------------------------
// K2: combine split-softmax partials per (lut, sample); target logit dot.
// Grid: 256 blocks (lut*128+b) x 256 threads (4 waves; was 64 -> ~4x faster).
// ---------------------------------------------------------------------------
__global__ __launch_bounds__(256) void k_reduce(
    const float* __restrict__ inputs, const int* __restrict__ targets,
    const float* __restrict__ lutc, const float* __restrict__ luti,
    const float* __restrict__ maxp, const float* __restrict__ sep,
    const float* __restrict__ slp, float* __restrict__ vvals)
{
    __shared__ float sM[4], sS[4], sSL[4], sDP;
    const int l    = blockIdx.x >> 7;
    const int b    = blockIdx.x & 127;
    const int tid  = threadIdx.x;
    const int wv   = tid >> 6;
    const int lane = tid & 63;
    const size_t base = ((size_t)(l * BB + b)) * NWG;

    float M = -3.0e38f, S = 0.f, SL = 0.f;
    for (int w = tid; w < NWG; w += 256) {
        float m = maxp[base + w];
        float s = sep[base + w];
        float nM = fmaxf(M, m);
        S = S * __expf(M - nM) + s * __expf(m - nM);
        M = nM;
        SL += slp[base + w];
    }
#pragma unroll
    for (int off = 1; off < 64; off <<= 1) {
        float m2 = __shfl_xor(M, off), s2 = __shfl_xor(S, off), sl2 = __shfl_xor(SL, off);
        float nM = fmaxf(M, m2);
        S = S * __expf(M - nM) + s2 * __expf(m2 - nM);
        M = nM;
        SL += sl2;
    }
    // target logit: wave 0 does the 256-feature fp32 dot
    if (wv == 0) {
        const int tgt = targets[b];
        const float* lut = (l == 0 ? lutc : luti) + (size_t)tgt * FF;
        const float* inp = inputs + (size_t)b * FF;
        float4 x = *(const float4*)(inp + lane * 4);
        float4 y = *(const float4*)(lut + lane * 4);
        float dp = x.x * y.x + x.y * y.y + x.z * y.z + x.w * y.w;
#pragma unroll
        for (int off = 1; off < 64; off <<= 1) dp += __shfl_xor(dp, off);
        if (lane == 0) sDP = dp;
    }
    if (lane == 0) { sM[wv] = M; sS[wv] = S; sSL[wv] = SL; }
    __syncthreads();
    if (tid == 0) {
        float m = fmaxf(fmaxf(sM[0], sM[1]), fmaxf(sM[2], sM[3]));
        float S4 = 0.f, SL4 = 0.f;
#pragma unroll
        for (int i = 0; i < 4; ++i) {
            S4  += sS[i] * __expf(sM[i] - m);
            SL4 += sSL[i];
        }
        float lt  = SCALARF * sDP;
        float lse = m + __logf(S4);
        // (1-eps)*(lse - l_t) + eps*(lse - mean(logits))
        vvals[blockIdx.x] = 0.9f * (lse - lt) + 0.1f * (lse - SL4 / (float)CC);
    }
}

// ---------------------------------------------------------------------------
// K3: final scalar reduction.
// ---------------------------------------------------------------------------
__global__ __launch_bounds__(256) void k_final(
    const float* __restrict__ vvals, const float* __restrict__ hubp,
    float* __restrict__ out)
{
    __shared__ float sv[4], sh2[4];
    const int tid = threadIdx.x;
    float v = vvals[tid];            // exactly 256 values
    float h = 0.f;
    for (int w = tid; w < NWG; w += 256) h += hubp[w];
#pragma unroll
    for (int off = 1; off < 64; off <<= 1) {
        v += __shfl_xor(v, off);
        h += __shfl_xor(h, off);
    }
    if ((tid & 63) == 0) { sv[tid >> 6] = v; sh2[tid >> 6] = h; }
    __syncthreads();
    if (tid == 0) {
        float sumv = sv[0] + sv[1] + sv[2] + sv[3];
        float sumh = sh2[0] + sh2[1] + sh2[2] + sh2[3];
        out[0] = sumv / (float)BB + 0.25f * sumh / ((float)BB * (float)CC);
    }
}

extern "C" void kernel_launch(void* const* d_in, const int* in_sizes, int n_in,
                              void* d_out, int out_size, void* d_ws, size_t ws_size,
                              hipStream_t stream) {
    const float* inputs  = (const float*)d_in[0];
    const int*   targets = (const int*)d_in[1];
    const float* lutc    = (const float*)d_in[2];
    const float* luti    = (const float*)d_in[3];
    float* out = (float*)d_out;
    float* ws  = (float*)d_ws;

    // ws layout (floats): maxp | sep | slp | hubp | vvals | wsA (128KB, ushort)
    const size_t statN = (size_t)2 * BB * NWG;   // 400128
    float* maxp  = ws;
    float* sep   = ws + statN;
    float* slp   = ws + 2 * statN;
    float* hubp  = ws + 3 * statN;
    float* vvals = hubp + NWG;
    unsigned short* wsA = (unsigned short*)(ws + 1202208);  // 16B-aligned, +128KB

    k_prep<<<16, 256, 0, stream>>>(inputs, wsA);
    k_main_mfma<<<NWG, 256, 0, stream>>>(wsA, lutc, luti, maxp, sep, slp, hubp);
    k_reduce<<<256, 256, 0, stream>>>(inputs, targets, lutc, luti, maxp, sep, slp, vvals);
    k_final<<<1, 256, 0, stream>>>(vvals, hubp, out);
}